// Round 8
// baseline (519.433 us; speedup 1.0000x reference)
//
#include <hip/hip_runtime.h>
#include <math.h>

#define HID 256
#define TD 32
#define NL 3
#define C1DIM 128
#define OUTDIM 2
#define QKVW 768

using half8  = __attribute__((ext_vector_type(8))) _Float16;
using half4v = __attribute__((ext_vector_type(4))) _Float16;
using half2v = __attribute__((ext_vector_type(2))) _Float16;
using f32x4  = __attribute__((ext_vector_type(4))) float;

typedef __attribute__((address_space(1))) void gbl_void_t;
typedef __attribute__((address_space(3))) void lds_void_t;

__device__ __forceinline__ void load16_to_lds(const void* g, void* l) {
  __builtin_amdgcn_global_load_lds((const gbl_void_t*)g, (lds_void_t*)l, 16, 0, 0);
}

__device__ __forceinline__ int sdot4i(unsigned a, unsigned b, int acc) {
#if __has_builtin(__builtin_amdgcn_sdot4)
  return __builtin_amdgcn_sdot4((int)a, (int)b, acc, false);
#else
#pragma unroll
  for (int i = 0; i < 4; ++i)
    acc += (int)(signed char)(a >> (8 * i)) * (int)(signed char)(b >> (8 * i));
  return acc;
#endif
}

// ---------- setup: ts min/max (single block) + zero deg ----------
__global__ __launch_bounds__(1024) void k_tsmm(const float* __restrict__ ts,
                                               float* __restrict__ mmf,
                                               int* __restrict__ deg, int n) {
  int t = threadIdx.x;
  float lmin = INFINITY, lmax = -INFINITY;
  for (int i = t; i < n; i += 1024) {
    float v = ts[i];
    lmin = fminf(lmin, v);
    lmax = fmaxf(lmax, v);
    deg[i] = 0;
  }
#pragma unroll
  for (int off = 32; off >= 1; off >>= 1) {
    lmin = fminf(lmin, __shfl_xor(lmin, off));
    lmax = fmaxf(lmax, __shfl_xor(lmax, off));
  }
  __shared__ float wmin[16], wmax[16];
  int lane = t & 63, w = t >> 6;
  if (lane == 0) { wmin[w] = lmin; wmax[w] = lmax; }
  __syncthreads();
  if (t == 0) {
    float a = INFINITY, b = -INFINITY;
    for (int i = 0; i < 16; ++i) { a = fminf(a, wmin[i]); b = fmaxf(b, wmax[i]); }
    mmf[0] = a; mmf[1] = b;
  }
}

// ---------- merged time encoding + x conversion ----------
__global__ void k_enc(const float* __restrict__ ts, const float* __restrict__ freq,
                      const float* __restrict__ mmf, const float* __restrict__ x,
                      _Float16* __restrict__ tfh, _Float16* __restrict__ xh, int n) {
  int idx = blockIdx.x * blockDim.x + threadIdx.x;
  int nt = n * TD;
  if (idx < nt) {
    int node = idx >> 5, j = idx & 31;
    float t = (ts[node] - mmf[0]) / (mmf[1] - mmf[0] + 1e-8f);
    float w = t * freq[j & 15];
    tfh[idx] = (_Float16)((j < 16) ? cosf(w) : sinf(w));
  } else if (idx < nt + n * 32) {
    int i2 = idx - nt;
    xh[i2] = (_Float16)x[i2];
  }
}

// ---------- merged weight prep ----------
__global__ void k_prep(const float* __restrict__ inW, const float* __restrict__ qW,
                       const float* __restrict__ kW, const float* __restrict__ vW,
                       const float* __restrict__ oW, const float* __restrict__ qb,
                       const float* __restrict__ kb, const float* __restrict__ vb,
                       _Float16* __restrict__ inWt, _Float16* __restrict__ qkvWt,
                       float* __restrict__ qkvb, _Float16* __restrict__ oWt) {
  int idx = blockIdx.x * blockDim.x + threadIdx.x;
  const int S0 = 32 * HID;
  const int KQ = HID + TD;
  const int S1 = NL * QKVW * KQ;
  const int S2 = NL * QKVW;
  const int S3 = NL * HID * HID;
  if (idx < S0) {
    int nrow = idx / 32, k = idx - nrow * 32;
    inWt[idx] = (_Float16)inW[k * HID + nrow];
  } else if ((idx -= S0) < S1) {
    int l = idx / (QKVW * KQ);
    int rem = idx - l * (QKVW * KQ);
    int nrow = rem / KQ;
    int k = rem - nrow * KQ;
    float v;
    if (nrow < 256)      v = qW[(size_t)l * KQ * HID + (size_t)k * HID + nrow];
    else if (nrow < 512) v = kW[(size_t)l * KQ * HID + (size_t)k * HID + (nrow - 256)];
    else                 v = (k < HID) ? vW[(size_t)l * HID * HID + (size_t)k * HID + (nrow - 512)] : 0.f;
    qkvWt[idx] = (_Float16)v;
  } else if ((idx -= S1) < S2) {
    int l = idx / QKVW;
    int j = idx - l * QKVW;
    float v;
    if (j < 256)      v = qb[l * HID + j];
    else if (j < 512) v = kb[l * HID + (j - 256)];
    else              v = vb[l * HID + (j - 512)];
    qkvb[idx] = v;
  } else if ((idx -= S2) < S3) {
    int l = idx / (HID * HID);
    int rem = idx - l * (HID * HID);
    int nrow = rem / HID;
    int k = rem - nrow * HID;
    oWt[idx] = (_Float16)oW[(size_t)l * HID * HID + (size_t)k * HID + nrow];
  }
}

__global__ void k_count(const int* __restrict__ dst, int* deg, int e) {
  int i = blockIdx.x * blockDim.x + threadIdx.x;
  if (i < e) atomicAdd(&deg[dst[i]], 1);
}

// ---------- 3-kernel scan ----------
__global__ __launch_bounds__(256) void k_scan_part(const int* __restrict__ deg,
                                                   int* __restrict__ bsum, int n) {
  int t = threadIdx.x;
  int idx = blockIdx.x * 256 + t;
  int v = (idx < n) ? deg[idx] : 0;
  int lane = t & 63, w = t >> 6;
  int x = v;
#pragma unroll
  for (int off = 1; off < 64; off <<= 1) {
    int y = __shfl_up(x, off);
    if (lane >= off) x += y;
  }
  __shared__ int ws[4];
  if (lane == 63) ws[w] = x;
  __syncthreads();
  if (t == 0) bsum[blockIdx.x] = ws[0] + ws[1] + ws[2] + ws[3];
}

__global__ __launch_bounds__(64) void k_scan_mid(const int* __restrict__ bsum,
                                                 int* __restrict__ boff, int nb) {
  int lane = threadIdx.x;
  int carry = 0;
  for (int base = 0; base < nb; base += 64) {
    int i = base + lane;
    int v = (i < nb) ? bsum[i] : 0;
    int x = v;
#pragma unroll
    for (int off = 1; off < 64; off <<= 1) {
      int y = __shfl_up(x, off);
      if (lane >= off) x += y;
    }
    if (i < nb) boff[i] = carry + x - v;
    carry += __shfl(x, 63);
  }
}

__global__ __launch_bounds__(256) void k_scan_apply(const int* __restrict__ deg,
                                                    const int* __restrict__ boff,
                                                    int* __restrict__ row_ptr,
                                                    int* __restrict__ cursor, int n, int e) {
  int t = threadIdx.x;
  int idx = blockIdx.x * 256 + t;
  int v = (idx < n) ? deg[idx] : 0;
  int lane = t & 63, w = t >> 6;
  int x = v;
#pragma unroll
  for (int off = 1; off < 64; off <<= 1) {
    int y = __shfl_up(x, off);
    if (lane >= off) x += y;
  }
  __shared__ int ws[4];
  if (lane == 63) ws[w] = x;
  __syncthreads();
  int wpre = 0;
  for (int i = 0; i < w; ++i) wpre += ws[i];
  if (idx < n) {
    row_ptr[idx] = boff[blockIdx.x] + wpre + x - v;
    cursor[idx] = 0;
  }
  if (idx == 0) row_ptr[n] = e;
}

__global__ void k_scatter(const int* __restrict__ src, const int* __restrict__ dst,
                          const int* __restrict__ row_ptr, int* cursor,
                          int* __restrict__ colbuf, int e) {
  int i = blockIdx.x * blockDim.x + threadIdx.x;
  if (i >= e) return;
  int d = dst[i];
  int p = atomicAdd(&cursor[d], 1);
  colbuf[row_ptr[d] + p] = src[i];
}

// ---------- fp16 MFMA GEMM (128x64 tile, BK=32, 4 waves) ----------
__global__ __launch_bounds__(256) void k_gemm_f16(
    const _Float16* __restrict__ A1, int K1,
    const _Float16* __restrict__ A2, int K2,
    const _Float16* __restrict__ Bt,
    const float* __restrict__ bias,
    _Float16* __restrict__ C,
    int M, int Ncols, int Ktot, int act) {
  __shared__ half8 smem8[2 * 768];
  char* smem = (char*)smem8;
  const int tid = threadIdx.x;
  const int lane = tid & 63, wave = tid >> 6;
  const int wm = wave >> 1, wn = wave & 1;
  const int row0 = blockIdx.y * 128;
  const int col0 = blockIdx.x * 64;

  auto stage = [&](int buf, int k0) {
    char* sA = smem + buf * 12288;
    char* sB = sA + 8192;
#pragma unroll
    for (int i = 0; i < 2; ++i) {
      int kg = i * 2 + (wave >> 1);
      int row = (wave & 1) * 64 + lane;
      int grow = row0 + row; if (grow > M - 1) grow = M - 1;
      int k = k0 + kg * 8;
      const _Float16* src = (k < K1) ? (A1 + (size_t)grow * K1 + k)
                                     : (A2 + (size_t)grow * K2 + (k - K1));
      load16_to_lds(src, sA + (i * 256 + wave * 64) * 16);
    }
    {
      const _Float16* src = Bt + (size_t)(col0 + lane) * Ktot + k0 + wave * 8;
      load16_to_lds(src, sB + wave * 64 * 16);
    }
  };

  f32x4 acc[4][2];
#pragma unroll
  for (int mf = 0; mf < 4; ++mf)
#pragma unroll
    for (int nf = 0; nf < 2; ++nf) acc[mf][nf] = f32x4{0.f, 0.f, 0.f, 0.f};

  const int nsteps = Ktot >> 5;
  int cur = 0;
  stage(0, 0);
  __syncthreads();
  for (int st = 0; st < nsteps; ++st) {
    if (st + 1 < nsteps) stage(cur ^ 1, (st + 1) * 32);
    char* sA = smem + cur * 12288;
    char* sB = sA + 8192;
    half8 af[4], bf[2];
#pragma unroll
    for (int mf = 0; mf < 4; ++mf) {
      int slot = (lane >> 4) * 128 + wm * 64 + mf * 16 + (lane & 15);
      af[mf] = *(const half8*)(sA + slot * 16);
    }
#pragma unroll
    for (int nf = 0; nf < 2; ++nf) {
      int slot = (lane >> 4) * 64 + wn * 32 + nf * 16 + (lane & 15);
      bf[nf] = *(const half8*)(sB + slot * 16);
    }
#pragma unroll
    for (int mf = 0; mf < 4; ++mf)
#pragma unroll
      for (int nf = 0; nf < 2; ++nf)
        acc[mf][nf] = __builtin_amdgcn_mfma_f32_16x16x32_f16(af[mf], bf[nf], acc[mf][nf], 0, 0, 0);
    __syncthreads();
    cur ^= 1;
  }

  const int rbase = row0 + wm * 64 + (lane >> 4) * 4;
  const int cbase = col0 + wn * 32 + (lane & 15);
#pragma unroll
  for (int nf = 0; nf < 2; ++nf) {
    int col = cbase + nf * 16;
    float bv = bias[col];
#pragma unroll
    for (int mf = 0; mf < 4; ++mf) {
#pragma unroll
      for (int r = 0; r < 4; ++r) {
        int row = rbase + mf * 16 + r;
        if (row < M) {
          float v = acc[mf][nf][r] + bv;
          if (act == 1) v = (v > 0.f) ? v : expm1f(v);
          C[(size_t)row * Ncols + col] = (_Float16)v;
        }
      }
    }
  }
}

// ---------- K/V fp16 -> int8, HEAD-MAJOR layout ----------
// KV8[h][node] = 64 B: 8 slots of {K 4B, V 4B}; slot j covers dims 4j..4j+4 of head h.
// SC[h*n + node] = half2 (sk, sv).
// one 32-thread group per node (thread: head=t32>>2, part p=t32&3 -> dims 8p..8p+8); 8 nodes/block
__global__ __launch_bounds__(256) void k_cvt8(const _Float16* __restrict__ QKV,
                                              unsigned char* __restrict__ KV8,
                                              half2v* __restrict__ SC, int n) {
  int node = blockIdx.x * 8 + (threadIdx.x >> 5);
  if (node >= n) return;
  int t32 = threadIdx.x & 31;
  int h = t32 >> 2, p = t32 & 3;
  const _Float16* base = QKV + (size_t)node * QKVW + t32 * 8;
  half8 kh = *(const half8*)(base + 256);
  half8 vh = *(const half8*)(base + 512);
  float kf[8], vf[8];
  float kmax = 0.f, vmax = 0.f;
#pragma unroll
  for (int j = 0; j < 8; ++j) {
    kf[j] = (float)kh[j]; kmax = fmaxf(kmax, fabsf(kf[j]));
    vf[j] = (float)vh[j]; vmax = fmaxf(vmax, fabsf(vf[j]));
  }
  // per-head (quad) max
  kmax = fmaxf(kmax, __shfl_xor(kmax, 1)); kmax = fmaxf(kmax, __shfl_xor(kmax, 2));
  vmax = fmaxf(vmax, __shfl_xor(vmax, 1)); vmax = fmaxf(vmax, __shfl_xor(vmax, 2));
  float kinv = (kmax > 0.f) ? (127.f / kmax) : 0.f;
  float vinv = (vmax > 0.f) ? (127.f / vmax) : 0.f;
  unsigned kp0 = 0, kp1 = 0, vp0 = 0, vp1 = 0;
#pragma unroll
  for (int j = 0; j < 4; ++j) {
    kp0 |= ((unsigned)((int)rintf(kf[j] * kinv)) & 255u) << (8 * j);
    kp1 |= ((unsigned)((int)rintf(kf[j + 4] * kinv)) & 255u) << (8 * j);
    vp0 |= ((unsigned)((int)rintf(vf[j] * vinv)) & 255u) << (8 * j);
    vp1 |= ((unsigned)((int)rintf(vf[j + 4] * vinv)) & 255u) << (8 * j);
  }
  unsigned char* out = KV8 + (((size_t)h * n + node) << 6);
  *(uint2*)(out + (2 * p) * 8)     = uint2{kp0, vp0};
  *(uint2*)(out + (2 * p + 1) * 8) = uint2{kp1, vp1};
  if (p == 0) {
    half2v sp;
    sp.x = (_Float16)(kmax * (1.f / 127.f));
    sp.y = (_Float16)(vmax * (1.f / 127.f));
    SC[(size_t)h * n + node] = sp;
  }
}

// ---------- attention: head-split, int8 K/V, L2-resident per XCD ----------
// head = blockIdx.x & 7 (XCD round-robin); 32 nodes/block, 8 threads/node (4 dims each)
__global__ __launch_bounds__(256) void k_attn(const _Float16* __restrict__ QKV,
                                              const unsigned char* __restrict__ KV8,
                                              const half2v* __restrict__ SC,
                                              const int* __restrict__ row_ptr,
                                              const int* __restrict__ colbuf,
                                              _Float16* __restrict__ out, int n) {
  int h = blockIdx.x & 7;
  int node = (blockIdx.x >> 3) * 32 + (threadIdx.x >> 3);
  if (node >= n) return;
  int j = threadIdx.x & 7;
  const float scale = 0.17677669529663687f;  // 1/sqrt(32)
  const unsigned char* KVh = KV8 + (((size_t)h * n) << 6);
  const half2v* SCh = SC + (size_t)h * n;

  // load + quantize Q (head h, dims 4j..4j+4), scale folded
  half4v qh = *(const half4v*)(QKV + (size_t)node * QKVW + h * 32 + j * 4);
  float qf[4];
#pragma unroll
  for (int q = 0; q < 4; ++q) qf[q] = (float)qh[q] * scale;
  float qmax = fmaxf(fmaxf(fabsf(qf[0]), fabsf(qf[1])), fmaxf(fabsf(qf[2]), fabsf(qf[3])));
  qmax = fmaxf(qmax, __shfl_xor(qmax, 1));
  qmax = fmaxf(qmax, __shfl_xor(qmax, 2));
  qmax = fmaxf(qmax, __shfl_xor(qmax, 4));
  float qinv = (qmax > 0.f) ? (127.f / qmax) : 0.f;
  float sq = qmax * (1.f / 127.f);
  unsigned q8 = 0;
#pragma unroll
  for (int q = 0; q < 4; ++q)
    q8 |= ((unsigned)((int)rintf(qf[q] * qinv)) & 255u) << (8 * q);

  int beg = row_ptr[node], end = row_ptr[node + 1];
  float m = -INFINITY, s = 0.f;
  float a[4] = {0.f, 0.f, 0.f, 0.f};

  for (int i = beg; i < end; i += 4) {
    uint2 kv[4];
    float sk[4], sv[4];
#pragma unroll
    for (int t = 0; t < 4; ++t) {
      int ii = i + t; if (ii > end - 1) ii = end - 1;
      int sn = colbuf[ii];
      kv[t] = *(const uint2*)(KVh + ((size_t)sn << 6) + j * 8);
      half2v sc = SCh[sn];
      sk[t] = (float)sc.x;
      sv[t] = (float)sc.y;
    }
    float p[4];
#pragma unroll
    for (int t = 0; t < 4; ++t) {
      int idot = sdot4i(kv[t].x, q8, 0);
      float pf = (float)idot;
      pf += __shfl_xor(pf, 1);
      pf += __shfl_xor(pf, 2);
      pf += __shfl_xor(pf, 4);
      pf *= sq * sk[t];
      if (i + t >= end) pf = -INFINITY;  // tail mask (t=0 always real)
      p[t] = pf;
    }
#pragma unroll
    for (int t = 0; t < 4; ++t) {
      float vf[4];
      vf[0] = (float)(int)(signed char)(kv[t].y);
      vf[1] = (float)(int)(signed char)(kv[t].y >> 8);
      vf[2] = (float)(int)(signed char)(kv[t].y >> 16);
      vf[3] = (float)(int)(signed char)(kv[t].y >> 24);
      float sc_ = p[t];
      if (sc_ <= m) {
        float e2 = __expf(sc_ - m);
        s += e2;
        float ev = e2 * sv[t];
#pragma unroll
        for (int q = 0; q < 4; ++q) a[q] = fmaf(ev, vf[q], a[q]);
      } else {
        float f = __expf(m - sc_);  // m=-inf on first real edge -> f=0
        s = s * f + 1.f;
        float ev = sv[t];
#pragma unroll
        for (int q = 0; q < 4; ++q) a[q] = fmaf(a[q], f, ev * vf[q]);
        m = sc_;
      }
    }
  }

  float inv = (s > 0.f) ? (1.f / s) : 0.f;
  half4v o;
#pragma unroll
  for (int q = 0; q < 4; ++q) o[q] = (_Float16)(a[q] * inv);
  *(half4v*)(out + (size_t)node * HID + h * 32 + j * 4) = o;
}

// ---------- pooling + classifier ----------
__global__ __launch_bounds__(256) void k_pool_partial(const _Float16* __restrict__ h,
                                                      float* __restrict__ partial, int n) {
  int b = blockIdx.x, t = threadIdx.x;
  float s = 0.f;
  for (int r = b; r < n; r += 256) s += (float)h[(size_t)r * HID + t];
  partial[b * HID + t] = s;
}

__global__ __launch_bounds__(256) void k_final(const float* __restrict__ partial,
                                               const float* __restrict__ c1W,
                                               const float* __restrict__ c1b,
                                               const float* __restrict__ c2W,
                                               const float* __restrict__ c2b,
                                               float* __restrict__ out, int n) {
  __shared__ float gl[HID];
  __shared__ float r1[C1DIM];
  int t = threadIdx.x;
  float s = 0.f;
  for (int b = 0; b < 256; b++) s += partial[b * HID + t];
  gl[t] = s / (float)n;
  __syncthreads();
  if (t < C1DIM) {
    float a = c1b[t];
    for (int k = 0; k < HID; k++) a += gl[k] * c1W[k * C1DIM + t];
    r1[t] = fmaxf(a, 0.f);
  }
  __syncthreads();
  if (t < OUTDIM) {
    float a = c2b[t];
    for (int k = 0; k < C1DIM; k++) a += r1[k] * c2W[k * OUTDIM + t];
    out[t] = a;
  }
}

// ---------- host launcher ----------
extern "C" void kernel_launch(void* const* d_in, const int* in_sizes, int n_in,
                              void* d_out, int out_size, void* d_ws, size_t ws_size,
                              hipStream_t stream) {
  const float* x    = (const float*)d_in[0];
  const float* ts   = (const float*)d_in[1];
  const int*   ei   = (const int*)d_in[2];
  const float* freq = (const float*)d_in[4];
  const float* inW  = (const float*)d_in[5];
  const float* inb  = (const float*)d_in[6];
  const float* qW   = (const float*)d_in[7];
  const float* qb   = (const float*)d_in[8];
  const float* kW   = (const float*)d_in[9];
  const float* kb   = (const float*)d_in[10];
  const float* vW   = (const float*)d_in[11];
  const float* vb   = (const float*)d_in[12];
  const float* oW   = (const float*)d_in[13];
  const float* ob   = (const float*)d_in[14];
  const float* c1W  = (const float*)d_in[15];
  const float* c1b  = (const float*)d_in[16];
  const float* c2W  = (const float*)d_in[17];
  const float* c2b  = (const float*)d_in[18];

  int n = in_sizes[1];
  int e = in_sizes[2] / 2;
  const int* src = ei;
  const int* dst = ei + e;
  int nb = (n + 255) / 256;

  char* w = (char*)d_ws;
  size_t off = 0;
  auto alloc = [&](size_t bytes) -> char* {
    char* p = w + off;
    off = (off + bytes + 255) & ~(size_t)255;
    return p;
  };
  _Float16* tfh     = (_Float16*)alloc((size_t)n * TD * 2);
  _Float16* xh      = (_Float16*)alloc((size_t)n * 32 * 2);
  _Float16* h       = (_Float16*)alloc((size_t)n * HID * 2);
  _Float16* QKV     = (_Float16*)alloc((size_t)n * QKVW * 2);
  unsigned char* KV8 = (unsigned char*)alloc((size_t)n * 512);
  half2v*   SC      = (half2v*)alloc((size_t)n * 8 * 4);
  _Float16* ao      = (_Float16*)alloc((size_t)n * HID * 2);
  _Float16* inWt    = (_Float16*)alloc((size_t)32 * HID * 2);
  _Float16* qkvWt   = (_Float16*)alloc((size_t)NL * QKVW * (HID + TD) * 2);
  float*    qkvb    = (float*)alloc((size_t)NL * QKVW * 4);
  _Float16* oWt     = (_Float16*)alloc((size_t)NL * HID * HID * 2);
  int*      deg     = (int*)alloc((size_t)n * 4);
  int*      cursor  = (int*)alloc((size_t)n * 4);
  int*      row_ptr = (int*)alloc((size_t)(n + 1) * 4);
  int*      colbuf  = (int*)alloc((size_t)e * 4);
  int*      bsum    = (int*)alloc((size_t)nb * 4);
  int*      boff    = (int*)alloc((size_t)nb * 4);
  float*    partial = (float*)alloc((size_t)256 * HID * 4);
  float*    mmf     = (float*)alloc(256);

  int b256 = 256;
  hipLaunchKernelGGL(k_tsmm, dim3(1), dim3(1024), 0, stream, ts, mmf, deg, n);
  hipLaunchKernelGGL(k_enc, dim3((n * 64 + 255) / 256), dim3(b256), 0, stream,
                     ts, freq, mmf, x, tfh, xh, n);
  {
    int total = 32 * HID + NL * QKVW * (HID + TD) + NL * QKVW + NL * HID * HID;
    hipLaunchKernelGGL(k_prep, dim3((total + 255) / 256), dim3(b256), 0, stream,
                       inW, qW, kW, vW, oW, qb, kb, vb, inWt, qkvWt, qkvb, oWt);
  }
  hipLaunchKernelGGL(k_count, dim3((e + 255) / 256), dim3(b256), 0, stream, dst, deg, e);
  hipLaunchKernelGGL(k_scan_part, dim3(nb), dim3(b256), 0, stream, deg, bsum, n);
  hipLaunchKernelGGL(k_scan_mid, dim3(1), dim3(64), 0, stream, bsum, boff, nb);
  hipLaunchKernelGGL(k_scan_apply, dim3(nb), dim3(b256), 0, stream, deg, boff, row_ptr, cursor, n, e);
  hipLaunchKernelGGL(k_scatter, dim3((e + 255) / 256), dim3(b256), 0, stream, src, dst, row_ptr, cursor, colbuf, e);

  dim3 ggrid_h(HID / 64, (n + 127) / 128);
  dim3 ggrid_qkv(QKVW / 64, (n + 127) / 128);
  hipLaunchKernelGGL(k_gemm_f16, ggrid_h, dim3(b256), 0, stream,
                     xh, 32, xh, 32, inWt, inb, h, n, HID, 32, 0);

  int nchunks = (n + 31) / 32;
  for (int l = 0; l < NL; ++l) {
    const _Float16* qkvWtl = qkvWt + (size_t)l * QKVW * (HID + TD);
    const float*    qkvbl  = qkvb + (size_t)l * QKVW;
    const _Float16* oWtl   = oWt + (size_t)l * HID * HID;
    hipLaunchKernelGGL(k_gemm_f16, ggrid_qkv, dim3(b256), 0, stream,
                       h, HID, tfh, TD, qkvWtl, qkvbl, QKV, n, QKVW, HID + TD, 0);
    hipLaunchKernelGGL(k_cvt8, dim3((n + 7) / 8), dim3(b256), 0, stream,
                       QKV, KV8, SC, n);
    hipLaunchKernelGGL(k_attn, dim3(nchunks * 8), dim3(b256), 0, stream,
                       QKV, KV8, SC, row_ptr, colbuf, ao, n);
    hipLaunchKernelGGL(k_gemm_f16, ggrid_h, dim3(b256), 0, stream,
                       ao, HID, ao, HID, oWtl, ob + l * HID, h, n, HID, HID, 1);
  }

  hipLaunchKernelGGL(k_pool_partial, dim3(256), dim3(b256), 0, stream, h, partial, n);
  hipLaunchKernelGGL(k_final, dim3(1), dim3(b256), 0, stream, partial, c1W, c1b, c2W, c2b, (float*)d_out, n);
}

// Round 9
// 481.075 us; speedup vs baseline: 1.0797x; 1.0797x over previous
//
#include <hip/hip_runtime.h>
#include <math.h>

#define HID 256
#define TD 32
#define NL 3
#define C1DIM 128
#define OUTDIM 2
#define QKVW 768

using half8  = __attribute__((ext_vector_type(8))) _Float16;
using half4v = __attribute__((ext_vector_type(4))) _Float16;
using half2v = __attribute__((ext_vector_type(2))) _Float16;
using f32x4  = __attribute__((ext_vector_type(4))) float;

typedef __attribute__((address_space(1))) void gbl_void_t;
typedef __attribute__((address_space(3))) void lds_void_t;

__device__ __forceinline__ void load16_to_lds(const void* g, void* l) {
  __builtin_amdgcn_global_load_lds((const gbl_void_t*)g, (lds_void_t*)l, 16, 0, 0);
}

__device__ __forceinline__ float dot8h(half8 a, half8 b, float acc) {
#if __has_builtin(__builtin_amdgcn_fdot2)
  union { half8 v; half2v h2[4]; } ua, ub;
  ua.v = a; ub.v = b;
#pragma unroll
  for (int j = 0; j < 4; ++j) acc = __builtin_amdgcn_fdot2(ua.h2[j], ub.h2[j], acc, false);
  return acc;
#else
#pragma unroll
  for (int j = 0; j < 8; ++j) acc += (float)a[j] * (float)b[j];
  return acc;
#endif
}

// ---------- setup: ts min/max (single block) + zero deg ----------
__global__ __launch_bounds__(1024) void k_tsmm(const float* __restrict__ ts,
                                               float* __restrict__ mmf,
                                               int* __restrict__ deg, int n) {
  int t = threadIdx.x;
  float lmin = INFINITY, lmax = -INFINITY;
  for (int i = t; i < n; i += 1024) {
    float v = ts[i];
    lmin = fminf(lmin, v);
    lmax = fmaxf(lmax, v);
    deg[i] = 0;
  }
#pragma unroll
  for (int off = 32; off >= 1; off >>= 1) {
    lmin = fminf(lmin, __shfl_xor(lmin, off));
    lmax = fmaxf(lmax, __shfl_xor(lmax, off));
  }
  __shared__ float wmin[16], wmax[16];
  int lane = t & 63, w = t >> 6;
  if (lane == 0) { wmin[w] = lmin; wmax[w] = lmax; }
  __syncthreads();
  if (t == 0) {
    float a = INFINITY, b = -INFINITY;
    for (int i = 0; i < 16; ++i) { a = fminf(a, wmin[i]); b = fmaxf(b, wmax[i]); }
    mmf[0] = a; mmf[1] = b;
  }
}

// ---------- merged time encoding + x conversion ----------
__global__ void k_enc(const float* __restrict__ ts, const float* __restrict__ freq,
                      const float* __restrict__ mmf, const float* __restrict__ x,
                      _Float16* __restrict__ tfh, _Float16* __restrict__ xh, int n) {
  int idx = blockIdx.x * blockDim.x + threadIdx.x;
  int nt = n * TD;
  if (idx < nt) {
    int node = idx >> 5, j = idx & 31;
    float t = (ts[node] - mmf[0]) / (mmf[1] - mmf[0] + 1e-8f);
    float w = t * freq[j & 15];
    tfh[idx] = (_Float16)((j < 16) ? cosf(w) : sinf(w));
  } else if (idx < nt + n * 32) {
    int i2 = idx - nt;
    xh[i2] = (_Float16)x[i2];
  }
}

// ---------- merged weight prep ----------
__global__ void k_prep(const float* __restrict__ inW, const float* __restrict__ qW,
                       const float* __restrict__ kW, const float* __restrict__ vW,
                       const float* __restrict__ oW, const float* __restrict__ qb,
                       const float* __restrict__ kb, const float* __restrict__ vb,
                       _Float16* __restrict__ inWt, _Float16* __restrict__ qkvWt,
                       float* __restrict__ qkvb, _Float16* __restrict__ oWt) {
  int idx = blockIdx.x * blockDim.x + threadIdx.x;
  const int S0 = 32 * HID;
  const int KQ = HID + TD;
  const int S1 = NL * QKVW * KQ;
  const int S2 = NL * QKVW;
  const int S3 = NL * HID * HID;
  if (idx < S0) {
    int nrow = idx / 32, k = idx - nrow * 32;
    inWt[idx] = (_Float16)inW[k * HID + nrow];
  } else if ((idx -= S0) < S1) {
    int l = idx / (QKVW * KQ);
    int rem = idx - l * (QKVW * KQ);
    int nrow = rem / KQ;
    int k = rem - nrow * KQ;
    float v;
    if (nrow < 256)      v = qW[(size_t)l * KQ * HID + (size_t)k * HID + nrow];
    else if (nrow < 512) v = kW[(size_t)l * KQ * HID + (size_t)k * HID + (nrow - 256)];
    else                 v = (k < HID) ? vW[(size_t)l * HID * HID + (size_t)k * HID + (nrow - 512)] : 0.f;
    qkvWt[idx] = (_Float16)v;
  } else if ((idx -= S1) < S2) {
    int l = idx / QKVW;
    int j = idx - l * QKVW;
    float v;
    if (j < 256)      v = qb[l * HID + j];
    else if (j < 512) v = kb[l * HID + (j - 256)];
    else              v = vb[l * HID + (j - 512)];
    qkvb[idx] = v;
  } else if ((idx -= S2) < S3) {
    int l = idx / (HID * HID);
    int rem = idx - l * (HID * HID);
    int nrow = rem / HID;
    int k = rem - nrow * HID;
    oWt[idx] = (_Float16)oW[(size_t)l * HID * HID + (size_t)k * HID + nrow];
  }
}

__global__ void k_count(const int* __restrict__ dst, int* deg, int e) {
  int i = blockIdx.x * blockDim.x + threadIdx.x;
  if (i < e) atomicAdd(&deg[dst[i]], 1);
}

// ---------- 3-kernel scan ----------
__global__ __launch_bounds__(256) void k_scan_part(const int* __restrict__ deg,
                                                   int* __restrict__ bsum, int n) {
  int t = threadIdx.x;
  int idx = blockIdx.x * 256 + t;
  int v = (idx < n) ? deg[idx] : 0;
  int lane = t & 63, w = t >> 6;
  int x = v;
#pragma unroll
  for (int off = 1; off < 64; off <<= 1) {
    int y = __shfl_up(x, off);
    if (lane >= off) x += y;
  }
  __shared__ int ws[4];
  if (lane == 63) ws[w] = x;
  __syncthreads();
  if (t == 0) bsum[blockIdx.x] = ws[0] + ws[1] + ws[2] + ws[3];
}

__global__ __launch_bounds__(64) void k_scan_mid(const int* __restrict__ bsum,
                                                 int* __restrict__ boff, int nb) {
  int lane = threadIdx.x;
  int carry = 0;
  for (int base = 0; base < nb; base += 64) {
    int i = base + lane;
    int v = (i < nb) ? bsum[i] : 0;
    int x = v;
#pragma unroll
    for (int off = 1; off < 64; off <<= 1) {
      int y = __shfl_up(x, off);
      if (lane >= off) x += y;
    }
    if (i < nb) boff[i] = carry + x - v;
    carry += __shfl(x, 63);
  }
}

__global__ __launch_bounds__(256) void k_scan_apply(const int* __restrict__ deg,
                                                    const int* __restrict__ boff,
                                                    int* __restrict__ row_ptr,
                                                    int* __restrict__ cursor, int n, int e) {
  int t = threadIdx.x;
  int idx = blockIdx.x * 256 + t;
  int v = (idx < n) ? deg[idx] : 0;
  int lane = t & 63, w = t >> 6;
  int x = v;
#pragma unroll
  for (int off = 1; off < 64; off <<= 1) {
    int y = __shfl_up(x, off);
    if (lane >= off) x += y;
  }
  __shared__ int ws[4];
  if (lane == 63) ws[w] = x;
  __syncthreads();
  int wpre = 0;
  for (int i = 0; i < w; ++i) wpre += ws[i];
  if (idx < n) {
    row_ptr[idx] = boff[blockIdx.x] + wpre + x - v;
    cursor[idx] = 0;
  }
  if (idx == 0) row_ptr[n] = e;
}

__global__ void k_scatter(const int* __restrict__ src, const int* __restrict__ dst,
                          const int* __restrict__ row_ptr, int* cursor,
                          int* __restrict__ colbuf, int e) {
  int i = blockIdx.x * blockDim.x + threadIdx.x;
  if (i >= e) return;
  int d = dst[i];
  int p = atomicAdd(&cursor[d], 1);
  colbuf[row_ptr[d] + p] = src[i];
}

// ---------- fp16 MFMA GEMM (128x64 tile, BK=32, 4 waves) ----------
// mode 0: plain C write; mode 1: ELU C write; mode 2: QKV split write
//   (col<256 -> Qb[row][col]; col in [256,512) -> K head-major; col>=512 -> V head-major)
// KV layout: KV[((h*M)+row)*64 + isV*32 + dim]  (_Float16; 128 B per (head,row))
__global__ __launch_bounds__(256) void k_gemm_f16(
    const _Float16* __restrict__ A1, int K1,
    const _Float16* __restrict__ A2, int K2,
    const _Float16* __restrict__ Bt,
    const float* __restrict__ bias,
    _Float16* __restrict__ C,
    _Float16* __restrict__ Qb,
    _Float16* __restrict__ KV,
    int M, int Ncols, int Ktot, int mode) {
  __shared__ half8 smem8[2 * 768];
  char* smem = (char*)smem8;
  const int tid = threadIdx.x;
  const int lane = tid & 63, wave = tid >> 6;
  const int wm = wave >> 1, wn = wave & 1;
  const int row0 = blockIdx.y * 128;
  const int col0 = blockIdx.x * 64;

  auto stage = [&](int buf, int k0) {
    char* sA = smem + buf * 12288;
    char* sB = sA + 8192;
#pragma unroll
    for (int i = 0; i < 2; ++i) {
      int kg = i * 2 + (wave >> 1);
      int row = (wave & 1) * 64 + lane;
      int grow = row0 + row; if (grow > M - 1) grow = M - 1;
      int k = k0 + kg * 8;
      const _Float16* src = (k < K1) ? (A1 + (size_t)grow * K1 + k)
                                     : (A2 + (size_t)grow * K2 + (k - K1));
      load16_to_lds(src, sA + (i * 256 + wave * 64) * 16);
    }
    {
      const _Float16* src = Bt + (size_t)(col0 + lane) * Ktot + k0 + wave * 8;
      load16_to_lds(src, sB + wave * 64 * 16);
    }
  };

  f32x4 acc[4][2];
#pragma unroll
  for (int mf = 0; mf < 4; ++mf)
#pragma unroll
    for (int nf = 0; nf < 2; ++nf) acc[mf][nf] = f32x4{0.f, 0.f, 0.f, 0.f};

  const int nsteps = Ktot >> 5;
  int cur = 0;
  stage(0, 0);
  __syncthreads();
  for (int st = 0; st < nsteps; ++st) {
    if (st + 1 < nsteps) stage(cur ^ 1, (st + 1) * 32);
    char* sA = smem + cur * 12288;
    char* sB = sA + 8192;
    half8 af[4], bf[2];
#pragma unroll
    for (int mf = 0; mf < 4; ++mf) {
      int slot = (lane >> 4) * 128 + wm * 64 + mf * 16 + (lane & 15);
      af[mf] = *(const half8*)(sA + slot * 16);
    }
#pragma unroll
    for (int nf = 0; nf < 2; ++nf) {
      int slot = (lane >> 4) * 64 + wn * 32 + nf * 16 + (lane & 15);
      bf[nf] = *(const half8*)(sB + slot * 16);
    }
#pragma unroll
    for (int mf = 0; mf < 4; ++mf)
#pragma unroll
      for (int nf = 0; nf < 2; ++nf)
        acc[mf][nf] = __builtin_amdgcn_mfma_f32_16x16x32_f16(af[mf], bf[nf], acc[mf][nf], 0, 0, 0);
    __syncthreads();
    cur ^= 1;
  }

  const int rbase = row0 + wm * 64 + (lane >> 4) * 4;
  const int cbase = col0 + wn * 32 + (lane & 15);
#pragma unroll
  for (int nf = 0; nf < 2; ++nf) {
    int col = cbase + nf * 16;
    float bv = bias[col];
    if (mode != 2) {
#pragma unroll
      for (int mf = 0; mf < 4; ++mf) {
#pragma unroll
        for (int r = 0; r < 4; ++r) {
          int row = rbase + mf * 16 + r;
          if (row < M) {
            float v = acc[mf][nf][r] + bv;
            if (mode == 1) v = (v > 0.f) ? v : expm1f(v);
            C[(size_t)row * Ncols + col] = (_Float16)v;
          }
        }
      }
    } else {
      bool isQ = col < 256;
      int cc = col - 256;
      int isV = cc >> 8;          // 0 = K, 1 = V (when !isQ)
      int c2 = cc & 255;
      int hh = c2 >> 5, dim = c2 & 31;
      size_t kvoff = ((size_t)hh * M) * 64 + isV * 32 + dim;
#pragma unroll
      for (int mf = 0; mf < 4; ++mf) {
#pragma unroll
        for (int r = 0; r < 4; ++r) {
          int row = rbase + mf * 16 + r;
          if (row < M) {
            float v = acc[mf][nf][r] + bv;
            if (isQ) Qb[(size_t)row * HID + col] = (_Float16)v;
            else     KV[kvoff + (size_t)row * 64] = (_Float16)v;
          }
        }
      }
    }
  }
}

// ---------- attention: head-split (L2-resident), fp16 K/V, 4 threads/node ----------
// head = blockIdx.x & 7 (XCD round-robin); 64 nodes/block, 4 threads/node (8 dims each)
__global__ __launch_bounds__(256) void k_attn(const _Float16* __restrict__ Qb,
                                              const _Float16* __restrict__ KV,
                                              const int* __restrict__ row_ptr,
                                              const int* __restrict__ colbuf,
                                              _Float16* __restrict__ out, int n) {
  int h = blockIdx.x & 7;
  int node = (blockIdx.x >> 3) * 64 + (threadIdx.x >> 2);
  if (node >= n) return;
  int j = threadIdx.x & 3;   // dims j*8 .. j*8+7
  const float scale = 0.17677669529663687f;  // 1/sqrt(32)
  const _Float16* KVh = KV + ((size_t)h * n) * 64;

  // Q for head h, pre-scaled, kept as fp16 for fdot2
  half8 qh = *(const half8*)(Qb + (size_t)node * HID + h * 32 + j * 8);
  half8 qs;
#pragma unroll
  for (int q = 0; q < 8; ++q) qs[q] = (_Float16)((float)qh[q] * scale);

  int beg = row_ptr[node], end = row_ptr[node + 1];
  float m = -INFINITY, s = 0.f;
  float a[8] = {0.f, 0.f, 0.f, 0.f, 0.f, 0.f, 0.f, 0.f};

  for (int i = beg; i < end; i += 4) {
    half8 kk[4], vv[4];
#pragma unroll
    for (int t = 0; t < 4; ++t) {
      int ii = i + t; if (ii > end - 1) ii = end - 1;
      int sn = colbuf[ii];
      const _Float16* b = KVh + ((size_t)sn) * 64 + j * 8;
      kk[t] = *(const half8*)(b);
      vv[t] = *(const half8*)(b + 32);
    }
    float p[4];
#pragma unroll
    for (int t = 0; t < 4; ++t) p[t] = dot8h(qs, kk[t], 0.f);
#pragma unroll
    for (int t = 0; t < 4; ++t) {
      p[t] += __shfl_xor(p[t], 1);
      p[t] += __shfl_xor(p[t], 2);
      if (i + t >= end) p[t] = -INFINITY;  // tail mask (t=0 always real)
    }
#pragma unroll
    for (int t = 0; t < 4; ++t) {
      float sc_ = p[t];
      if (sc_ <= m) {
        float e2 = __expf(sc_ - m);
        s += e2;
#pragma unroll
        for (int q = 0; q < 8; ++q) a[q] = fmaf(e2, (float)vv[t][q], a[q]);
      } else {
        float f = __expf(m - sc_);  // m=-inf on first real edge -> f=0
        s = s * f + 1.f;
#pragma unroll
        for (int q = 0; q < 8; ++q) a[q] = fmaf(a[q], f, (float)vv[t][q]);
        m = sc_;
      }
    }
  }

  float inv = (s > 0.f) ? (1.f / s) : 0.f;
  half8 o;
#pragma unroll
  for (int q = 0; q < 8; ++q) o[q] = (_Float16)(a[q] * inv);
  *(half8*)(out + (size_t)node * HID + h * 32 + j * 8) = o;
}

// ---------- pooling + classifier ----------
__global__ __launch_bounds__(256) void k_pool_partial(const _Float16* __restrict__ h,
                                                      float* __restrict__ partial, int n) {
  int b = blockIdx.x, t = threadIdx.x;
  float s = 0.f;
  for (int r = b; r < n; r += 256) s += (float)h[(size_t)r * HID + t];
  partial[b * HID + t] = s;
}

__global__ __launch_bounds__(256) void k_final(const float* __restrict__ partial,
                                               const float* __restrict__ c1W,
                                               const float* __restrict__ c1b,
                                               const float* __restrict__ c2W,
                                               const float* __restrict__ c2b,
                                               float* __restrict__ out, int n) {
  __shared__ float gl[HID];
  __shared__ float r1[C1DIM];
  int t = threadIdx.x;
  float s = 0.f;
  for (int b = 0; b < 256; b++) s += partial[b * HID + t];
  gl[t] = s / (float)n;
  __syncthreads();
  if (t < C1DIM) {
    float a = c1b[t];
    for (int k = 0; k < HID; k++) a += gl[k] * c1W[k * C1DIM + t];
    r1[t] = fmaxf(a, 0.f);
  }
  __syncthreads();
  if (t < OUTDIM) {
    float a = c2b[t];
    for (int k = 0; k < C1DIM; k++) a += r1[k] * c2W[k * OUTDIM + t];
    out[t] = a;
  }
}

// ---------- host launcher ----------
extern "C" void kernel_launch(void* const* d_in, const int* in_sizes, int n_in,
                              void* d_out, int out_size, void* d_ws, size_t ws_size,
                              hipStream_t stream) {
  const float* x    = (const float*)d_in[0];
  const float* ts   = (const float*)d_in[1];
  const int*   ei   = (const int*)d_in[2];
  const float* freq = (const float*)d_in[4];
  const float* inW  = (const float*)d_in[5];
  const float* inb  = (const float*)d_in[6];
  const float* qW   = (const float*)d_in[7];
  const float* qb   = (const float*)d_in[8];
  const float* kW   = (const float*)d_in[9];
  const float* kb   = (const float*)d_in[10];
  const float* vW   = (const float*)d_in[11];
  const float* vb   = (const float*)d_in[12];
  const float* oW   = (const float*)d_in[13];
  const float* ob   = (const float*)d_in[14];
  const float* c1W  = (const float*)d_in[15];
  const float* c1b  = (const float*)d_in[16];
  const float* c2W  = (const float*)d_in[17];
  const float* c2b  = (const float*)d_in[18];

  int n = in_sizes[1];
  int e = in_sizes[2] / 2;
  const int* src = ei;
  const int* dst = ei + e;
  int nb = (n + 255) / 256;

  char* w = (char*)d_ws;
  size_t off = 0;
  auto alloc = [&](size_t bytes) -> char* {
    char* p = w + off;
    off = (off + bytes + 255) & ~(size_t)255;
    return p;
  };
  _Float16* tfh     = (_Float16*)alloc((size_t)n * TD * 2);
  _Float16* xh      = (_Float16*)alloc((size_t)n * 32 * 2);
  _Float16* h       = (_Float16*)alloc((size_t)n * HID * 2);
  _Float16* Qbuf    = (_Float16*)alloc((size_t)n * HID * 2);
  _Float16* KV      = (_Float16*)alloc((size_t)n * 512 * 2);  // 8 heads x 64 halves
  _Float16* ao      = (_Float16*)alloc((size_t)n * HID * 2);
  _Float16* inWt    = (_Float16*)alloc((size_t)32 * HID * 2);
  _Float16* qkvWt   = (_Float16*)alloc((size_t)NL * QKVW * (HID + TD) * 2);
  float*    qkvb    = (float*)alloc((size_t)NL * QKVW * 4);
  _Float16* oWt     = (_Float16*)alloc((size_t)NL * HID * HID * 2);
  int*      deg     = (int*)alloc((size_t)n * 4);
  int*      cursor  = (int*)alloc((size_t)n * 4);
  int*      row_ptr = (int*)alloc((size_t)(n + 1) * 4);
  int*      colbuf  = (int*)alloc((size_t)e * 4);
  int*      bsum    = (int*)alloc((size_t)nb * 4);
  int*      boff    = (int*)alloc((size_t)nb * 4);
  float*    partial = (float*)alloc((size_t)256 * HID * 4);
  float*    mmf     = (float*)alloc(256);

  int b256 = 256;
  hipLaunchKernelGGL(k_tsmm, dim3(1), dim3(1024), 0, stream, ts, mmf, deg, n);
  hipLaunchKernelGGL(k_enc, dim3((n * 64 + 255) / 256), dim3(b256), 0, stream,
                     ts, freq, mmf, x, tfh, xh, n);
  {
    int total = 32 * HID + NL * QKVW * (HID + TD) + NL * QKVW + NL * HID * HID;
    hipLaunchKernelGGL(k_prep, dim3((total + 255) / 256), dim3(b256), 0, stream,
                       inW, qW, kW, vW, oW, qb, kb, vb, inWt, qkvWt, qkvb, oWt);
  }
  hipLaunchKernelGGL(k_count, dim3((e + 255) / 256), dim3(b256), 0, stream, dst, deg, e);
  hipLaunchKernelGGL(k_scan_part, dim3(nb), dim3(b256), 0, stream, deg, bsum, n);
  hipLaunchKernelGGL(k_scan_mid, dim3(1), dim3(64), 0, stream, bsum, boff, nb);
  hipLaunchKernelGGL(k_scan_apply, dim3(nb), dim3(b256), 0, stream, deg, boff, row_ptr, cursor, n, e);
  hipLaunchKernelGGL(k_scatter, dim3((e + 255) / 256), dim3(b256), 0, stream, src, dst, row_ptr, cursor, colbuf, e);

  dim3 ggrid_h(HID / 64, (n + 127) / 128);
  dim3 ggrid_qkv(QKVW / 64, (n + 127) / 128);
  hipLaunchKernelGGL(k_gemm_f16, ggrid_h, dim3(b256), 0, stream,
                     xh, 32, xh, 32, inWt, inb, h, (_Float16*)nullptr, (_Float16*)nullptr,
                     n, HID, 32, 0);

  int nchunks = (n + 63) / 64;
  for (int l = 0; l < NL; ++l) {
    const _Float16* qkvWtl = qkvWt + (size_t)l * QKVW * (HID + TD);
    const float*    qkvbl  = qkvb + (size_t)l * QKVW;
    const _Float16* oWtl   = oWt + (size_t)l * HID * HID;
    hipLaunchKernelGGL(k_gemm_f16, ggrid_qkv, dim3(b256), 0, stream,
                       h, HID, tfh, TD, qkvWtl, qkvbl, (_Float16*)nullptr, Qbuf, KV,
                       n, QKVW, HID + TD, 2);
    hipLaunchKernelGGL(k_attn, dim3(nchunks * 8), dim3(b256), 0, stream,
                       Qbuf, KV, row_ptr, colbuf, ao, n);
    hipLaunchKernelGGL(k_gemm_f16, ggrid_h, dim3(b256), 0, stream,
                       ao, HID, ao, HID, oWtl, ob + l * HID, h, (_Float16*)nullptr, (_Float16*)nullptr,
                       n, HID, HID, 1);
  }

  hipLaunchKernelGGL(k_pool_partial, dim3(256), dim3(b256), 0, stream, h, partial, n);
  hipLaunchKernelGGL(k_final, dim3(1), dim3(b256), 0, stream, partial, c1W, c1b, c2W, c2b, (float*)d_out, n);
}